// Round 3
// baseline (753.207 us; speedup 1.0000x reference)
//
#include <hip/hip_runtime.h>
#include <hip/hip_bf16.h>
#include <stdint.h>

typedef __bf16 bf16_t;
typedef bf16_t bf16x8 __attribute__((ext_vector_type(8)));
typedef float f32x4 __attribute__((ext_vector_type(4)));

#define GAS __attribute__((address_space(1)))
#define LAS __attribute__((address_space(3)))

__device__ __forceinline__ void async_load16(const void* g, void* l) {
    __builtin_amdgcn_global_load_lds((const GAS void*)g, (LAS void*)l, 16, 0, 0);
}
// compiler-fence + HW barrier (s_barrier alone is not a compiler memory fence)
__device__ __forceinline__ void hw_barrier() {
    asm volatile("" ::: "memory");
    __builtin_amdgcn_s_barrier();
    asm volatile("" ::: "memory");
}

// ---------- phase 1 (grid-stride): cast x->bf16  +  dequant W->bf16 ----------
__global__ __launch_bounds__(256) void prep_kernel(
    const float* __restrict__ x, bf16_t* __restrict__ xb,
    const int* __restrict__ wp, const float* __restrict__ cen,
    const float* __restrict__ scl, bf16_t* __restrict__ W,
    int castBlocks, long nCastChunks, int nDeqChunks)
{
    if ((int)blockIdx.x < castBlocks) {
        long idx    = (long)blockIdx.x * blockDim.x + threadIdx.x;
        long stride = (long)castBlocks * blockDim.x;
        const float4* xv = (const float4*)x;
        bf16x8* xo = (bf16x8*)xb;
        for (long t = idx; t < nCastChunks; t += stride) {
            float4 a = xv[2 * t];
            float4 b = xv[2 * t + 1];
            bf16x8 o;
            o[0] = (bf16_t)a.x; o[1] = (bf16_t)a.y; o[2] = (bf16_t)a.z; o[3] = (bf16_t)a.w;
            o[4] = (bf16_t)b.x; o[5] = (bf16_t)b.y; o[6] = (bf16_t)b.z; o[7] = (bf16_t)b.w;
            xo[t] = o;
        }
    } else {
        __shared__ float c[16];
        if (threadIdx.x < 16) c[threadIdx.x] = cen[threadIdx.x];
        __syncthreads();
        int  nb     = (int)gridDim.x - castBlocks;
        long idx    = (long)((int)blockIdx.x - castBlocks) * blockDim.x + threadIdx.x;
        long stride = (long)nb * blockDim.x;
        const int4* wv = (const int4*)wp;
        bf16x8* wo = (bf16x8*)W;
        for (long t = idx; t < (long)nDeqChunks; t += stride) {
            int4 v = wv[t];
            long p   = t << 2;
            int  o   = (int)(p >> 11);
            int  pin = (int)p & 2047;
            float s = scl[(o << 6) + (pin >> 5)];
            int vv[4] = {v.x, v.y, v.z, v.w};
            bf16x8 outv;
#pragma unroll
            for (int i = 0; i < 4; ++i) {
                int b = vv[i];
                outv[2 * i]     = (bf16_t)(c[(b >> 4) & 15] * s);
                outv[2 * i + 1] = (bf16_t)(c[b & 15] * s);
            }
            wo[t] = outv;
        }
    }
}

// ---------------- phase 2: bf16 NT GEMM, 256x128 tile, BK=64, TRIPLE buffer ----------------
// 8 waves (4M x 2N), per-wave output 64x64 (acc[4][4] f32x4, the proven shape).
// LDS: 3 x (A 256x64 + B 128x64) bf16 = 144 KB. Tile t lives in buf t%3.
// Invariant at tile t start: tile t fully landed (all waves), tile t+1's 6 loads
// in flight, buf (t+2)%3 reader-free (its readers finished at tile t-1's end).
// Per tile: 2 phases, each {3 stage-issues (tile t+2) -> ds_reads -> barrier ->
// lgkmcnt(0) -> setprio(1) -> 16 MFMA -> setprio(0) -> barrier}. End of tile:
// vmcnt(6) (own t+2 loads = 6 outstanding allowed -> all t+1 loads retired),
// then barrier => every wave's t+1 loads landed. Counted vmcnt, never 0 in
// steady state; tile t+1's loads get a full K-tile of compute to fly.
// XOR swizzle at 16B-chunk granularity (verified 0 bank conflicts): global kc
// pre-swizzled kc^(row&7), LDS dest linear, frag read col (kc^(qm&7))*8.
#define BM 256
#define BN 128
#define BK 64
#define NBUF 3

__global__ __launch_bounds__(512, 1) void gemm_bf16_nt(
    const bf16_t* __restrict__ A, const bf16_t* __restrict__ B,
    float* __restrict__ C, int M, int N, int K)
{
    __shared__ bf16_t lA[NBUF * BM * BK];   // 96 KB
    __shared__ bf16_t lB[NBUF * BN * BK];   // 48 KB

    const int tid  = threadIdx.x;
    const int wave = tid >> 6;
    const int lane = tid & 63;
    const int wm4  = (wave >> 1) * 64;   // M base in tile (4 M-waves)
    const int wn2  = (wave & 1) * 64;    // N base in tile (2 N-waves)

    // XCD-aware swizzle (nwg = 1024, % 8 == 0 -> simple form bijective)
    const int nwg = (int)gridDim.x;
    const int cpx = nwg >> 3;
    const int bid = (int)blockIdx.x;
    const int swz = (bid & 7) * cpx + (bid >> 3);
    const int nx  = N / BN;
    const int by  = swz / nx;
    const int bx  = swz - by * nx;
    const long m0 = (long)by * BM;
    const long n0 = (long)bx * BN;

    // staging: A 2048 chunks (4 rounds x 512), B 1024 chunks (2 rounds x 512).
    // slot s = r*512+tid: row=s>>3, global kc=(s&7)^(row&7); LDS dest linear.
    int offA[4], offB[2], ldsA[4], ldsB[2];
#pragma unroll
    for (int r = 0; r < 4; ++r) {
        int s = r * 512 + tid;
        int row = s >> 3;
        int kg = (s & 7) ^ (row & 7);
        offA[r] = (int)(m0 + row) * K + kg * 8;
        ldsA[r] = (r * 512 + wave * 64) * 8;   // wave-uniform elem offset
    }
#pragma unroll
    for (int r = 0; r < 2; ++r) {
        int s = r * 512 + tid;
        int row = s >> 3;
        int kg = (s & 7) ^ (row & 7);
        offB[r] = (int)(n0 + row) * K + kg * 8;
        ldsB[r] = (r * 512 + wave * 64) * 8;
    }

    const int qm  = lane & 15;
    const int kcb = lane >> 4;                  // 0..3
    const int co0 = (kcb ^ (qm & 7)) * 8;       // K half 0 chunk offset (elems)
    const int co1 = ((kcb + 4) ^ (qm & 7)) * 8; // K half 1

    f32x4 acc[4][4] = {};

    // prologue: stage tiles 0 (buf0) and 1 (buf1); wait tile0; barrier.
#pragma unroll
    for (int r = 0; r < 4; ++r) async_load16(A + offA[r], lA + ldsA[r]);
#pragma unroll
    for (int r = 0; r < 2; ++r) async_load16(B + offB[r], lB + ldsB[r]);
#pragma unroll
    for (int r = 0; r < 4; ++r) async_load16(A + offA[r] + BK, lA + BM * BK + ldsA[r]);
#pragma unroll
    for (int r = 0; r < 2; ++r) async_load16(B + offB[r] + BK, lB + BN * BK + ldsB[r]);
    asm volatile("s_waitcnt vmcnt(6)" ::: "memory");   // tile0's 6 retired (in-order)
    hw_barrier();

    const int NT = K / BK;   // 64
    int cb = 0, sb = 2;
    for (int t = 0; t < NT; ++t) {
        const bf16_t* la = lA + cb * (BM * BK);
        const bf16_t* lb = lB + cb * (BN * BK);
        bf16_t* sa = lA + sb * (BM * BK);
        bf16_t* sv = lB + sb * (BN * BK);
        const int  kt2     = (t + 2) * BK;
        const bool doStage = (t + 2 < NT);

        bf16x8 bfr[4][2], af[2][2];

        // ---------------- phase 0: A frags 0,1 x all B ----------------
        if (doStage) {
            async_load16(A + offA[0] + kt2, sa + ldsA[0]);
            async_load16(A + offA[1] + kt2, sa + ldsA[1]);
            async_load16(B + offB[0] + kt2, sv + ldsB[0]);
        }
#pragma unroll
        for (int j = 0; j < 4; ++j) {
            const bf16_t* pb = lb + (wn2 + j * 16 + qm) * BK;
            bfr[j][0] = *(const bf16x8*)(pb + co0);
            bfr[j][1] = *(const bf16x8*)(pb + co1);
        }
#pragma unroll
        for (int i = 0; i < 2; ++i) {
            const bf16_t* pa = la + (wm4 + i * 16 + qm) * BK;
            af[i][0] = *(const bf16x8*)(pa + co0);
            af[i][1] = *(const bf16x8*)(pa + co1);
        }
        hw_barrier();
        asm volatile("s_waitcnt lgkmcnt(0)" ::: "memory");
        __builtin_amdgcn_sched_barrier(0);
        __builtin_amdgcn_s_setprio(1);
#pragma unroll
        for (int i = 0; i < 2; ++i)
#pragma unroll
            for (int j = 0; j < 4; ++j) {
                acc[i][j] = __builtin_amdgcn_mfma_f32_16x16x32_bf16(af[i][0], bfr[j][0], acc[i][j], 0, 0, 0);
                acc[i][j] = __builtin_amdgcn_mfma_f32_16x16x32_bf16(af[i][1], bfr[j][1], acc[i][j], 0, 0, 0);
            }
        __builtin_amdgcn_s_setprio(0);
        hw_barrier();

        // ---------------- phase 1: A frags 2,3 x all B (B reused from regs) ----------------
        if (doStage) {
            async_load16(A + offA[2] + kt2, sa + ldsA[2]);
            async_load16(A + offA[3] + kt2, sa + ldsA[3]);
            async_load16(B + offB[1] + kt2, sv + ldsB[1]);
        }
#pragma unroll
        for (int i = 0; i < 2; ++i) {
            const bf16_t* pa = la + (wm4 + (i + 2) * 16 + qm) * BK;
            af[i][0] = *(const bf16x8*)(pa + co0);
            af[i][1] = *(const bf16x8*)(pa + co1);
        }
        hw_barrier();
        asm volatile("s_waitcnt lgkmcnt(0)" ::: "memory");
        __builtin_amdgcn_sched_barrier(0);
        __builtin_amdgcn_s_setprio(1);
#pragma unroll
        for (int i = 0; i < 2; ++i)
#pragma unroll
            for (int j = 0; j < 4; ++j) {
                acc[i + 2][j] = __builtin_amdgcn_mfma_f32_16x16x32_bf16(af[i][0], bfr[j][0], acc[i + 2][j], 0, 0, 0);
                acc[i + 2][j] = __builtin_amdgcn_mfma_f32_16x16x32_bf16(af[i][1], bfr[j][1], acc[i + 2][j], 0, 0, 0);
            }
        __builtin_amdgcn_s_setprio(0);
        // tile boundary: own outstanding = 6 (t+2) + leftovers(t+1); vmcnt(6)
        // retires ALL of t+1's; barrier makes it collective.
        if (doStage)              asm volatile("s_waitcnt vmcnt(6)" ::: "memory");
        else if (t + 1 < NT)      asm volatile("s_waitcnt vmcnt(0)" ::: "memory");
        hw_barrier();

        cb = (cb == NBUF - 1) ? 0 : cb + 1;
        sb = (sb == NBUF - 1) ? 0 : sb + 1;
    }

    // C/D layout: col = lane&15, row = (lane>>4)*4 + reg   [m89-verified]
    const int crow = (lane >> 4) * 4;
    const int ccol = lane & 15;
#pragma unroll
    for (int i = 0; i < 4; ++i)
#pragma unroll
        for (int r = 0; r < 4; ++r) {
            float* cp = C + (m0 + wm4 + i * 16 + crow + r) * (long)N + (n0 + wn2 + ccol);
#pragma unroll
            for (int j = 0; j < 4; ++j)
                cp[j * 16] = acc[i][j][r];
        }
}

// ---------------- fallback (only if ws too small): fused, slow, correct ----------------
__global__ void fallback_qgemm(const float* __restrict__ x, const int* __restrict__ wp,
                               const float* __restrict__ cen, const float* __restrict__ scl,
                               float* __restrict__ out, int M, int N, int Kp) {
    __shared__ float c[16];
    if (threadIdx.x < 16) c[threadIdx.x] = cen[threadIdx.x];
    __syncthreads();
    int n = blockIdx.x * blockDim.x + threadIdx.x;
    int m = blockIdx.y;
    if (n >= N) return;
    const float* xr = x + (long)m * (Kp * 2);
    const int*   wr = wp + (long)n * Kp;
    int nb = Kp / 32;
    float acc = 0.f;
    for (int b = 0; b < nb; ++b) {
        float s  = scl[n * nb + b];
        float pa = 0.f;
        for (int j = 0; j < 32; ++j) {
            int v = wr[b * 32 + j];
            pa += xr[(b * 32 + j) * 2]     * c[(v >> 4) & 15]
                + xr[(b * 32 + j) * 2 + 1] * c[v & 15];
        }
        acc += s * pa;
    }
    out[(long)m * N + n] = acc;
}

extern "C" void kernel_launch(void* const* d_in, const int* in_sizes, int n_in,
                              void* d_out, int out_size, void* d_ws, size_t ws_size,
                              hipStream_t stream) {
    const float* x   = (const float*)d_in[0];
    const int*   wp  = (const int*)d_in[1];
    const float* cen = (const float*)d_in[2];
    const float* scl = (const float*)d_in[3];
    float* out = (float*)d_out;

    const int  IN  = 4096;
    const int  OUT = 4096;
    const long M   = (long)in_sizes[0] / IN;   // 8192

    size_t need = (size_t)(M * IN + (long)OUT * IN) * sizeof(bf16_t);  // 96 MB
    if (ws_size >= need && (M % BM) == 0) {
        bf16_t* xb = (bf16_t*)d_ws;
        bf16_t* Wb = xb + M * IN;
        const int castBlocks = 2048;
        const int deqBlocks  = 512;
        long nCastChunks = M * IN / 8;
        int  nDeqChunks  = OUT * (IN / 2) / 4;
        prep_kernel<<<dim3(castBlocks + deqBlocks), dim3(256), 0, stream>>>(
            x, xb, wp, cen, scl, Wb, castBlocks, nCastChunks, nDeqChunks);
        int nwg = (OUT / BN) * (int)(M / BM);   // 32 * 32 = 1024
        gemm_bf16_nt<<<dim3(nwg), dim3(512), 0, stream>>>(xb, Wb, out, (int)M, OUT, IN);
    } else {
        dim3 grid(OUT / 256, (unsigned)M);
        fallback_qgemm<<<grid, dim3(256), 0, stream>>>(x, wp, cen, scl, out, (int)M, OUT, IN / 2);
    }
}

// Round 4
// 521.724 us; speedup vs baseline: 1.4437x; 1.4437x over previous
//
#include <hip/hip_runtime.h>
#include <hip/hip_bf16.h>
#include <stdint.h>

typedef __bf16 bf16_t;
typedef bf16_t bf16x8 __attribute__((ext_vector_type(8)));
typedef float f32x4 __attribute__((ext_vector_type(4)));
typedef float f32x16 __attribute__((ext_vector_type(16)));

#define GAS __attribute__((address_space(1)))
#define LAS __attribute__((address_space(3)))

__device__ __forceinline__ void async_load16(const void* g, void* l) {
    __builtin_amdgcn_global_load_lds((const GAS void*)g, (LAS void*)l, 16, 0, 0);
}

// ---------- phase 1 (grid-stride): cast x->bf16  +  dequant W->bf16 ----------
__global__ __launch_bounds__(256) void prep_kernel(
    const float* __restrict__ x, bf16_t* __restrict__ xb,
    const int* __restrict__ wp, const float* __restrict__ cen,
    const float* __restrict__ scl, bf16_t* __restrict__ W,
    int castBlocks, long nCastChunks, int nDeqChunks)
{
    if ((int)blockIdx.x < castBlocks) {
        long idx    = (long)blockIdx.x * blockDim.x + threadIdx.x;
        long stride = (long)castBlocks * blockDim.x;
        const float4* xv = (const float4*)x;
        bf16x8* xo = (bf16x8*)xb;
        for (long t = idx; t < nCastChunks; t += stride) {
            float4 a = xv[2 * t];
            float4 b = xv[2 * t + 1];
            bf16x8 o;
            o[0] = (bf16_t)a.x; o[1] = (bf16_t)a.y; o[2] = (bf16_t)a.z; o[3] = (bf16_t)a.w;
            o[4] = (bf16_t)b.x; o[5] = (bf16_t)b.y; o[6] = (bf16_t)b.z; o[7] = (bf16_t)b.w;
            xo[t] = o;
        }
    } else {
        __shared__ float c[16];
        if (threadIdx.x < 16) c[threadIdx.x] = cen[threadIdx.x];
        __syncthreads();
        int  nb     = (int)gridDim.x - castBlocks;
        long idx    = (long)((int)blockIdx.x - castBlocks) * blockDim.x + threadIdx.x;
        long stride = (long)nb * blockDim.x;
        const int4* wv = (const int4*)wp;
        bf16x8* wo = (bf16x8*)W;
        for (long t = idx; t < (long)nDeqChunks; t += stride) {
            int4 v = wv[t];
            long p   = t << 2;
            int  o   = (int)(p >> 11);
            int  pin = (int)p & 2047;
            float s = scl[(o << 6) + (pin >> 5)];
            int vv[4] = {v.x, v.y, v.z, v.w};
            bf16x8 outv;
#pragma unroll
            for (int i = 0; i < 4; ++i) {
                int b = vv[i];
                outv[2 * i]     = (bf16_t)(c[(b >> 4) & 15] * s);
                outv[2 * i + 1] = (bf16_t)(c[b & 15] * s);
            }
            wo[t] = outv;
        }
    }
}

// ---------------- phase 2: bf16 NT GEMM, 128x128 tile, BK=64 ----------------
// REVERT to the proven Round-0 structure (244us, MfmaUtil 55%, 0 bank conflicts,
// 4 blocks/CU inter-block overlap) with ONE change: 16x16x32 -> 32x32x16 MFMA
// (measured issue ceiling 2075 -> 2495 TF, half the MFMA instruction count).
// 4 waves (2x2), per-wave 64x64 = 2x2 fragments of 32x32, acc[2][2] f32x16.
// A-operand layout: row=lane&31, k=(lane>>5)*8+j (analog of verified 16x16 map).
// C/D layout: col=lane&31, row=(reg&3)+8*(reg>>2)+4*(lane>>5)  [m74/m101].
// LDS + staging + XOR swizzle identical to Round-0: (row,kc)->slot kc^(row&7)
// at 16B-chunk granularity, global source pre-swizzled, LDS dest linear.
// Frag-read chunk for k-step s (k=s*16+hk*8+j): kc=2s+hk, co=(kc^(row&7))*8.
// Bank pattern per 16-lane quarter identical to Round-0's (2-way, free).
#define BM 128
#define BN 128
#define BK 64

__global__ __launch_bounds__(256, 4) void gemm_bf16_nt(
    const bf16_t* __restrict__ A, const bf16_t* __restrict__ B,
    float* __restrict__ C, int M, int N, int K)
{
    __shared__ bf16_t lA[BM * BK];   // 16 KB
    __shared__ bf16_t lB[BN * BK];   // 16 KB

    const int tid  = threadIdx.x;
    const int wave = tid >> 6;
    const int lane = tid & 63;
    const int wm   = (wave >> 1) * 64;
    const int wn   = (wave & 1) * 64;

    const long m0 = (long)blockIdx.y * BM;
    const long n0 = (long)blockIdx.x * BN;

    // staging: 1024 chunks per matrix, 4 rounds of 256 threads (unchanged).
    // slot s = r*256 + tid : row = s>>3, kc_slot = s&7, global kc = kc_slot^(row&7)
    const bf16_t* aP[4];
    const bf16_t* bP[4];
    int ldsOff[4];
#pragma unroll
    for (int r = 0; r < 4; ++r) {
        int s   = r * 256 + tid;
        int row = s >> 3;
        int kg  = (s & 7) ^ (row & 7);
        aP[r] = A + (m0 + row) * K + kg * 8;
        bP[r] = B + (n0 + row) * K + kg * 8;
        ldsOff[r] = (r * 256 + wave * 64) * 8;   // wave-uniform elem offset
    }

    // fragment addressing for 32x32x16
    const int r31 = lane & 31;          // row-in-fragment (A) / col (B)
    const int hk  = lane >> 5;          // k-half-of-8 selector
    const int sw  = lane & 7;           // swizzle key == row&7 (frag bases %32==0)
    const bf16_t* pa0 = lA + (wm + r31) * BK;          // i=0 row
    const bf16_t* pa1 = lA + (wm + 32 + r31) * BK;     // i=1 row
    const bf16_t* pb0 = lB + (wn + r31) * BK;
    const bf16_t* pb1 = lB + (wn + 32 + r31) * BK;
    int co[4];
#pragma unroll
    for (int s = 0; s < 4; ++s) co[s] = ((2 * s + hk) ^ sw) * 8;

    f32x16 acc[2][2] = {};

    for (int k0 = 0; k0 < K; k0 += BK) {
#pragma unroll
        for (int r = 0; r < 4; ++r) async_load16(aP[r] + k0, lA + ldsOff[r]);
#pragma unroll
        for (int r = 0; r < 4; ++r) async_load16(bP[r] + k0, lB + ldsOff[r]);
        __syncthreads();

        bf16x8 af[2][2], bfv[2][2];
        // half 0: k-steps s=0,1
#pragma unroll
        for (int s = 0; s < 2; ++s) {
            af[0][s]  = *(const bf16x8*)(pa0 + co[s]);
            af[1][s]  = *(const bf16x8*)(pa1 + co[s]);
            bfv[0][s] = *(const bf16x8*)(pb0 + co[s]);
            bfv[1][s] = *(const bf16x8*)(pb1 + co[s]);
        }
#pragma unroll
        for (int s = 0; s < 2; ++s)
#pragma unroll
            for (int i = 0; i < 2; ++i)
#pragma unroll
                for (int j = 0; j < 2; ++j)
                    acc[i][j] = __builtin_amdgcn_mfma_f32_32x32x16_bf16(af[i][s], bfv[j][s], acc[i][j], 0, 0, 0);
        // half 1: k-steps s=2,3
#pragma unroll
        for (int s = 0; s < 2; ++s) {
            af[0][s]  = *(const bf16x8*)(pa0 + co[s + 2]);
            af[1][s]  = *(const bf16x8*)(pa1 + co[s + 2]);
            bfv[0][s] = *(const bf16x8*)(pb0 + co[s + 2]);
            bfv[1][s] = *(const bf16x8*)(pb1 + co[s + 2]);
        }
#pragma unroll
        for (int s = 0; s < 2; ++s)
#pragma unroll
            for (int i = 0; i < 2; ++i)
#pragma unroll
                for (int j = 0; j < 2; ++j)
                    acc[i][j] = __builtin_amdgcn_mfma_f32_32x32x16_bf16(af[i][s], bfv[j][s], acc[i][j], 0, 0, 0);
        __syncthreads();
    }

    // C/D: col = lane&31, row = (reg&3) + 8*(reg>>2) + 4*(lane>>5)  [m74/m101]
    const int ccol = r31;
#pragma unroll
    for (int i = 0; i < 2; ++i)
#pragma unroll
        for (int r = 0; r < 16; ++r) {
            int crow = (r & 3) + 8 * (r >> 2) + 4 * hk;
            float* cp = C + (m0 + wm + i * 32 + crow) * (long)N + (n0 + wn + ccol);
#pragma unroll
            for (int j = 0; j < 2; ++j)
                cp[j * 32] = acc[i][j][r];
        }
}

// ---------------- fallback (only if ws too small): fused, slow, correct ----------------
__global__ void fallback_qgemm(const float* __restrict__ x, const int* __restrict__ wp,
                               const float* __restrict__ cen, const float* __restrict__ scl,
                               float* __restrict__ out, int M, int N, int Kp) {
    __shared__ float c[16];
    if (threadIdx.x < 16) c[threadIdx.x] = cen[threadIdx.x];
    __syncthreads();
    int n = blockIdx.x * blockDim.x + threadIdx.x;
    int m = blockIdx.y;
    if (n >= N) return;
    const float* xr = x + (long)m * (Kp * 2);
    const int*   wr = wp + (long)n * Kp;
    int nb = Kp / 32;
    float acc = 0.f;
    for (int b = 0; b < nb; ++b) {
        float s  = scl[n * nb + b];
        float pa = 0.f;
        for (int j = 0; j < 32; ++j) {
            int v = wr[b * 32 + j];
            pa += xr[(b * 32 + j) * 2]     * c[(v >> 4) & 15]
                + xr[(b * 32 + j) * 2 + 1] * c[v & 15];
        }
        acc += s * pa;
    }
    out[(long)m * N + n] = acc;
}

extern "C" void kernel_launch(void* const* d_in, const int* in_sizes, int n_in,
                              void* d_out, int out_size, void* d_ws, size_t ws_size,
                              hipStream_t stream) {
    const float* x   = (const float*)d_in[0];
    const int*   wp  = (const int*)d_in[1];
    const float* cen = (const float*)d_in[2];
    const float* scl = (const float*)d_in[3];
    float* out = (float*)d_out;

    const int  IN  = 4096;
    const int  OUT = 4096;
    const long M   = (long)in_sizes[0] / IN;   // 8192

    size_t need = (size_t)(M * IN + (long)OUT * IN) * sizeof(bf16_t);  // 96 MB
    if (ws_size >= need && (M % BM) == 0) {
        bf16_t* xb = (bf16_t*)d_ws;
        bf16_t* Wb = xb + M * IN;
        const int castBlocks = 2048;
        const int deqBlocks  = 512;
        long nCastChunks = M * IN / 8;
        int  nDeqChunks  = OUT * (IN / 2) / 4;
        prep_kernel<<<dim3(castBlocks + deqBlocks), dim3(256), 0, stream>>>(
            x, xb, wp, cen, scl, Wb, castBlocks, nCastChunks, nDeqChunks);
        dim3 grid(OUT / BN, (unsigned)(M / BM));
        gemm_bf16_nt<<<grid, dim3(256), 0, stream>>>(xb, Wb, out, (int)M, OUT, IN);
    } else {
        dim3 grid(OUT / 256, (unsigned)M);
        fallback_qgemm<<<grid, dim3(256), 0, stream>>>(x, wp, cen, scl, out, (int)M, OUT, IN / 2);
    }
}